// Round 3
// baseline (95.773 us; speedup 1.0000x reference)
//
#include <hip/hip_runtime.h>
#include <hip/hip_bf16.h>

#define BB 8
#define FF 4096
#define SS 1024
#define DD 128
#define DLL 256
#define NF (BB*FF)     // 32768 facts
#define NMSG (2*NF)    // 65536 message slots
#define NNODE (BB*SS)  // 8192 (b,s) rows
#define FPB 32         // facts per msg block (64 messages)

typedef short  short8 __attribute__((ext_vector_type(8)));
typedef float  f32x4  __attribute__((ext_vector_type(4)));

__device__ __forceinline__ float gelu_exact(float x) {
    return 0.5f * x * (1.0f + erff(x * 0.70710678118654752440f));
}

__device__ __forceinline__ ushort f2bf(float x) {
    uint u = __float_as_uint(x);
    uint r = (u + 0x7fffu + ((u >> 16) & 1u)) >> 16;
    return (ushort)r;
}

// ---------------------------------------------------------------------------
// Prep: bf16 embeddings; bf16 w1T[256][384], w2T[128][256].
// ---------------------------------------------------------------------------
#define N_POS   (SS*DD)
#define N_PRED_ (14*DD)
#define N_W1    (384*256)
#define N_W2    (256*128)
#define N_PREP  (N_POS + N_PRED_ + N_W1 + N_W2)

__global__ __launch_bounds__(256) void prep_kernel(
    const float* __restrict__ pos, const float* __restrict__ pred,
    const float* __restrict__ w1,  const float* __restrict__ w2,
    ushort* __restrict__ pos_bf, ushort* __restrict__ pred_bf,
    ushort* __restrict__ w1T,    ushort* __restrict__ w2T)
{
    int i = blockIdx.x * 256 + threadIdx.x;
    if (i < N_POS) { pos_bf[i] = f2bf(pos[i]); return; }
    i -= N_POS;
    if (i < N_PRED_) { pred_bf[i] = f2bf(pred[i]); return; }
    i -= N_PRED_;
    if (i < N_W1) { int k = i >> 8, n = i & 255; w1T[n*384 + k] = f2bf(w1[i]); return; }
    i -= N_W1;
    if (i < N_W2) { int k = i >> 7, d = i & 127; w2T[d*256 + k] = f2bf(w2[i]); return; }
}

// ---------------------------------------------------------------------------
// CSR build: count -> scan -> fill.  msg slot i = fact*2 + parity.
// parity 0 -> dest a1 (weight 1); parity 1 -> dest a0 (weight bidir, skip 0).
// ---------------------------------------------------------------------------
__global__ __launch_bounds__(256) void count_kernel(
    const int* __restrict__ a0, const int* __restrict__ a1,
    const float* __restrict__ bidir, int* __restrict__ cnt)
{
    int i = blockIdx.x * 256 + threadIdx.x;   // 0..NMSG-1
    int g = i >> 1, p = i & 1;
    float w = p ? bidir[g] : 1.0f;
    if (w != 0.0f) {
        int node = p ? a0[g] : a1[g];
        atomicAdd(&cnt[((g >> 12) << 10) + node], 1);
    }
}

__global__ __launch_bounds__(1024) void scan_kernel(
    const int* __restrict__ cnt, int* __restrict__ off, int* __restrict__ cur)
{
    __shared__ int sd[1024];
    const int t = threadIdx.x;
    int v[8]; int s = 0;
    #pragma unroll
    for (int i = 0; i < 8; ++i) { v[i] = cnt[t*8 + i]; s += v[i]; }
    sd[t] = s; __syncthreads();
    for (int o = 1; o < 1024; o <<= 1) {
        int x = sd[t];
        if (t >= o) x += sd[t - o];
        __syncthreads(); sd[t] = x; __syncthreads();
    }
    int excl = sd[t] - s;
    #pragma unroll
    for (int i = 0; i < 8; ++i) { off[t*8 + i] = excl; cur[t*8 + i] = excl; excl += v[i]; }
    if (t == 1023) off[NNODE] = excl;
}

__global__ __launch_bounds__(256) void fill_kernel(
    const int* __restrict__ a0, const int* __restrict__ a1,
    const float* __restrict__ bidir, int* __restrict__ cur,
    int* __restrict__ idxlist)
{
    int i = blockIdx.x * 256 + threadIdx.x;
    int g = i >> 1, p = i & 1;
    float w = p ? bidir[g] : 1.0f;
    if (w != 0.0f) {
        int node = p ? a0[g] : a1[g];
        int pos = atomicAdd(&cur[((g >> 12) << 10) + node], 1);
        idxlist[pos] = i;
    }
}

// ---------------------------------------------------------------------------
// msg kernel (MFMA, swapped operands -> outputs indexed [n][m]/[d][m]).
// mode=1: store bf16 message rows to msgbuf (CSR path).
// mode=0: fp32 atomic scatter into agg (fallback).
// ---------------------------------------------------------------------------
__global__ __launch_bounds__(256, 4) void msg_kernel(
    const int* __restrict__ a0, const int* __restrict__ a1,
    const int* __restrict__ pidx, const float* __restrict__ bidir,
    const ushort* __restrict__ pos_bf, const ushort* __restrict__ pred_bf,
    const ushort* __restrict__ w1T, const float* __restrict__ b1,
    const ushort* __restrict__ w2T, const float* __restrict__ b2,
    ushort* __restrict__ msgbuf, float* __restrict__ agg, int mode)
{
    __shared__ uint4 shm[2048];           // union: xs (1536 u4) / h1 (2048 u4)
    __shared__ int   sa0[FPB], sa1[FPB], spi[FPB];
    __shared__ float sbid[FPB];

    const int tid = threadIdx.x;
    const int fbase = blockIdx.x * FPB;
    const int wid = tid >> 6, lane = tid & 63;
    const int lq = lane >> 4, lr = lane & 15;
    const int factL = lr >> 1, par = lr & 1;

    if (tid < FPB) {
        int g = fbase + tid;
        sa0[tid] = a0[g]; sa1[tid] = a1[g]; spi[tid] = pidx[g]; sbid[tid] = bidir[g];
    }
    __syncthreads();

    // ---- stage gathered inputs (bf16, 16B units, XOR-swizzled by fact&7) ----
    for (int U = tid; U < FPB * 48; U += 256) {
        int f = U / 48, u = U - 48 * f;
        int seg = u >> 4, du = u & 15;
        int row = (seg == 0) ? sa0[f] : ((seg == 1) ? spi[f] : sa1[f]);
        const uint4* src = (const uint4*)(((seg == 1) ? pred_bf : pos_bf) + row * DD) + du;
        shm[f * 48 + (u ^ (f & 7))] = *src;
    }
    __syncthreads();

    // ---- GEMM1: D1[n][m], acc[nf][mf] ----
    f32x4 acc[4][4];
    #pragma unroll
    for (int nf = 0; nf < 4; ++nf)
        #pragma unroll
        for (int mf = 0; mf < 4; ++mf) acc[nf][mf] = (f32x4)0.0f;

    for (int ks = 0; ks < 12; ++ks) {
        const int k_el = ks * 32 + lq * 8;
        const int seg = ks >> 2;
        const int kp = k_el + (par ? (seg == 0 ? 256 : (seg == 2 ? -256 : 0)) : 0);
        const int uq = (kp >> 3) ^ factL;
        short8 xfrag[4];
        #pragma unroll
        for (int mf = 0; mf < 4; ++mf)
            xfrag[mf] = *(const short8*)&shm[(mf * 8 + factL) * 48 + uq];
        short8 wfrag[4];
        #pragma unroll
        for (int nf = 0; nf < 4; ++nf)
            wfrag[nf] = *(const short8*)(w1T + (wid * 64 + nf * 16 + lr) * 384 + k_el);
        #pragma unroll
        for (int nf = 0; nf < 4; ++nf)
            #pragma unroll
            for (int mf = 0; mf < 4; ++mf)
                acc[nf][mf] = __builtin_amdgcn_mfma_f32_16x16x32_bf16(wfrag[nf], xfrag[mf], acc[nf][mf], 0, 0, 0);
    }
    __syncthreads();   // xs dead; reuse LDS as h1[64][256] bf16 (swizzled)

    // ---- bias + gelu + packed h1 store (ds_write_b64) ----
    #pragma unroll
    for (int nf = 0; nf < 4; ++nf) {
        const float4 bj = *(const float4*)(b1 + wid * 64 + nf * 16 + lq * 4);
        #pragma unroll
        for (int mf = 0; mf < 4; ++mf) {
            const int m = mf * 16 + lr;
            uint2 t;
            t.x = (uint)f2bf(gelu_exact(acc[nf][mf][0] + bj.x)) |
                  ((uint)f2bf(gelu_exact(acc[nf][mf][1] + bj.y)) << 16);
            t.y = (uint)f2bf(gelu_exact(acc[nf][mf][2] + bj.z)) |
                  ((uint)f2bf(gelu_exact(acc[nf][mf][3] + bj.w)) << 16);
            const int col = wid * 128 + nf * 32 + lq * 8;   // byte col = n0*2
            const int byteoff = m * 512 + (((col >> 4) ^ (m & 15)) << 4) + (col & 15);
            *(uint2*)((char*)shm + byteoff) = t;
        }
    }
    __syncthreads();

    // ---- GEMM2: D2[d][m], acc2[nf][mf] ----
    f32x4 acc2[2][4];
    #pragma unroll
    for (int nf = 0; nf < 2; ++nf)
        #pragma unroll
        for (int mf = 0; mf < 4; ++mf) acc2[nf][mf] = (f32x4)0.0f;

    for (int ks = 0; ks < 8; ++ks) {
        short8 hfrag[4];
        #pragma unroll
        for (int mf = 0; mf < 4; ++mf) {
            const int m = mf * 16 + lr;
            hfrag[mf] = *(const short8*)((char*)shm + m * 512 + ((((ks * 4 + lq)) ^ (m & 15)) << 4));
        }
        short8 w2frag[2];
        #pragma unroll
        for (int nf = 0; nf < 2; ++nf)
            w2frag[nf] = *(const short8*)(w2T + (wid * 32 + nf * 16 + lr) * 256 + ks * 32 + lq * 8);
        #pragma unroll
        for (int nf = 0; nf < 2; ++nf)
            #pragma unroll
            for (int mf = 0; mf < 4; ++mf)
                acc2[nf][mf] = __builtin_amdgcn_mfma_f32_16x16x32_bf16(w2frag[nf], hfrag[mf], acc2[nf][mf], 0, 0, 0);
    }

    // ---- epilogue: bias, bidir weight, store/scatter ----
    #pragma unroll
    for (int nf = 0; nf < 2; ++nf) {
        const float4 bd = *(const float4*)(b2 + wid * 32 + nf * 16 + lq * 4);
        const int d0 = wid * 32 + nf * 16 + lq * 4;
        #pragma unroll
        for (int mf = 0; mf < 4; ++mf) {
            const int m = mf * 16 + lr;
            const int fl = m >> 1;
            const float w = par ? sbid[fl] : 1.0f;
            float v0 = (acc2[nf][mf][0] + bd.x) * w;
            float v1 = (acc2[nf][mf][1] + bd.y) * w;
            float v2 = (acc2[nf][mf][2] + bd.z) * w;
            float v3 = (acc2[nf][mf][3] + bd.w) * w;
            if (mode) {
                if (w != 0.0f) {
                    uint2 t;
                    t.x = (uint)f2bf(v0) | ((uint)f2bf(v1) << 16);
                    t.y = (uint)f2bf(v2) | ((uint)f2bf(v3) << 16);
                    *(uint2*)(msgbuf + (size_t)(fbase * 2 + m) * DD + d0) = t;
                }
            } else {
                if (w != 0.0f) {
                    const int node = par ? sa0[fl] : sa1[fl];
                    const int b = fbase >> 12;
                    float* dst = agg + ((size_t)((b << 10) + node)) * DD + d0;
                    atomicAdd(dst + 0, v0);
                    atomicAdd(dst + 1, v1);
                    atomicAdd(dst + 2, v2);
                    atomicAdd(dst + 3, v3);
                }
            }
        }
    }
}

// ---------------------------------------------------------------------------
// Fused segment-reduce + LayerNorm + pool.  One wave per node, 4 nodes/wave.
// ---------------------------------------------------------------------------
#define NPW 4
__global__ __launch_bounds__(256) void reduce_kernel(
    const float* __restrict__ pos_emb, const ushort* __restrict__ msgbuf,
    const int* __restrict__ off, const int* __restrict__ idxlist,
    const float* __restrict__ ln_g, const float* __restrict__ ln_b,
    float* __restrict__ pooled)
{
    const int wave = threadIdx.x >> 6, lane = threadIdx.x & 63;
    const int nid0 = blockIdx.x * (4 * NPW) + wave * NPW;
    const int b = nid0 >> 10;
    const float2 g2  = *(const float2*)(ln_g + 2 * lane);
    const float2 bb2 = *(const float2*)(ln_b + 2 * lane);
    float p0 = 0.0f, p1 = 0.0f;

    for (int i = 0; i < NPW; ++i) {
        const int nid = nid0 + i;
        const int s = nid & (SS - 1);
        float2 h = *(const float2*)(pos_emb + s * DD + 2 * lane);
        const int j1 = off[nid + 1];
        for (int j = off[nid]; j < j1; ++j) {
            const int mslot = idxlist[j];
            const uint u = *(const uint*)(msgbuf + (size_t)mslot * DD + 2 * lane);
            h.x += __uint_as_float((u & 0xffffu) << 16);
            h.y += __uint_as_float(u & 0xffff0000u);
        }
        float sum = h.x + h.y;
        #pragma unroll
        for (int o = 32; o > 0; o >>= 1) sum += __shfl_xor(sum, o);
        const float mu = sum * (1.0f / 128.0f);
        const float d0 = h.x - mu, d1 = h.y - mu;
        float sq = d0 * d0 + d1 * d1;
        #pragma unroll
        for (int o = 32; o > 0; o >>= 1) sq += __shfl_xor(sq, o);
        const float rstd = rsqrtf(sq * (1.0f / 128.0f) + 1e-5f);
        p0 += d0 * rstd * g2.x + bb2.x;
        p1 += d1 * rstd * g2.y + bb2.y;
    }

    __shared__ float red[4][128];
    red[wave][2 * lane]     = p0;
    red[wave][2 * lane + 1] = p1;
    __syncthreads();
    if (threadIdx.x < 128) {
        const float v = red[0][threadIdx.x] + red[1][threadIdx.x]
                      + red[2][threadIdx.x] + red[3][threadIdx.x];
        atomicAdd(&pooled[b * DD + threadIdx.x], v);
    }
}

// ---------------------------------------------------------------------------
// Fallback LN+pool over agg (atomic path only)
// ---------------------------------------------------------------------------
__global__ __launch_bounds__(256) void ln_pool_kernel(
    const float* __restrict__ pos_emb, const float* __restrict__ agg,
    const float* __restrict__ ln_g, const float* __restrict__ ln_b,
    float* __restrict__ pooled)
{
    const int b = blockIdx.x / (SS / 32);
    const int s0 = (blockIdx.x % (SS / 32)) * 32;
    const int wave = threadIdx.x >> 6;
    const int lane = threadIdx.x & 63;
    const float g0 = ln_g[lane], g1 = ln_g[lane + 64];
    const float bb0 = ln_b[lane], bb1 = ln_b[lane + 64];
    float accp0 = 0.0f, accp1 = 0.0f;
    for (int r = 0; r < 8; ++r) {
        const int s = s0 + wave * 8 + r;
        const float* aggrow = agg + (size_t)(b*SS + s) * DD;
        const float* noderow = pos_emb + s * DD;
        const float h0 = noderow[lane]      + aggrow[lane];
        const float h1 = noderow[lane + 64] + aggrow[lane + 64];
        float sum = h0 + h1;
        #pragma unroll
        for (int o = 32; o > 0; o >>= 1) sum += __shfl_xor(sum, o);
        const float mu = sum * (1.0f / 128.0f);
        const float d0 = h0 - mu, d1 = h1 - mu;
        float sq = d0*d0 + d1*d1;
        #pragma unroll
        for (int o = 32; o > 0; o >>= 1) sq += __shfl_xor(sq, o);
        const float rstd = rsqrtf(sq * (1.0f / 128.0f) + 1e-5f);
        accp0 += d0 * rstd * g0 + bb0;
        accp1 += d1 * rstd * g1 + bb1;
    }
    __shared__ float red[4][128];
    red[wave][lane]      = accp0;
    red[wave][lane + 64] = accp1;
    __syncthreads();
    if (threadIdx.x < 128) {
        const float v = red[0][threadIdx.x] + red[1][threadIdx.x]
                      + red[2][threadIdx.x] + red[3][threadIdx.x];
        atomicAdd(&pooled[b*DD + threadIdx.x], v);
    }
}

// ---------------------------------------------------------------------------
// Latent head
// ---------------------------------------------------------------------------
__global__ __launch_bounds__(256) void head_kernel(
    const float* __restrict__ pooled,
    const float* __restrict__ lw1, const float* __restrict__ lb1,
    const float* __restrict__ lw2, const float* __restrict__ lb2,
    float* __restrict__ out)
{
    const int b = blockIdx.x;
    const int j = threadIdx.x;
    __shared__ float p[128];
    __shared__ float t1[256];
    if (j < 128) p[j] = pooled[b*DD + j] * (1.0f / (float)SS);
    __syncthreads();
    float acc = lb1[j];
    for (int k = 0; k < 128; ++k) acc += p[k] * lw1[k*256 + j];
    t1[j] = gelu_exact(acc);
    __syncthreads();
    float acc2 = lb2[j];
    for (int k = 0; k < 256; ++k) acc2 += t1[k] * lw2[k*256 + j];
    out[b*DLL + j] = acc2;
}

extern "C" void kernel_launch(void* const* d_in, const int* in_sizes, int n_in,
                              void* d_out, int out_size, void* d_ws, size_t ws_size,
                              hipStream_t stream) {
    const int*   a0       = (const int*)d_in[0];
    const int*   a1       = (const int*)d_in[1];
    const int*   pidx     = (const int*)d_in[2];
    const float* bidir    = (const float*)d_in[3];
    const float* pos_emb  = (const float*)d_in[4];
    const float* pred_emb = (const float*)d_in[5];
    const float* w1       = (const float*)d_in[6];
    const float* b1       = (const float*)d_in[7];
    const float* w2       = (const float*)d_in[8];
    const float* b2       = (const float*)d_in[9];
    const float* ln_g     = (const float*)d_in[10];
    const float* ln_b     = (const float*)d_in[11];
    const float* lw1      = (const float*)d_in[12];
    const float* lb1      = (const float*)d_in[13];
    const float* lw2      = (const float*)d_in[14];
    const float* lb2      = (const float*)d_in[15];

    char* ws = (char*)d_ws;

    // CSR layout
    const size_t O_MSG   = 0;                       // 16 MB  (NMSG*128 bf16)
    const size_t O_CNT   = 16777216;                // 32 KB
    const size_t O_POOL  = O_CNT + 32768;           // 4 KB   (memset with cnt)
    const size_t O_OFF   = O_POOL + 4096;           // (NNODE+1)*4 -> 32800
    const size_t O_CUR   = O_OFF + 32800;           // 32 KB
    const size_t O_IDX   = O_CUR + 32768;           // 256 KB
    const size_t O_PBF   = O_IDX + 262144;          // 256 KB
    const size_t O_PRBF  = O_PBF + 262144;          // 3.5 KB
    const size_t O_W1T   = O_PRBF + 3584;           // 192 KB
    const size_t O_W2T   = O_W1T + 196608;          // 64 KB
    const size_t CSR_NEED = O_W2T + 65536;          // ~17.7 MB

    if (ws_size >= CSR_NEED) {
        ushort* msgbuf = (ushort*)(ws + O_MSG);
        int*    cnt    = (int*)(ws + O_CNT);
        float*  pooled = (float*)(ws + O_POOL);
        int*    off    = (int*)(ws + O_OFF);
        int*    cur    = (int*)(ws + O_CUR);
        int*    idxl   = (int*)(ws + O_IDX);
        ushort* pos_bf = (ushort*)(ws + O_PBF);
        ushort* pred_bf= (ushort*)(ws + O_PRBF);
        ushort* w1T    = (ushort*)(ws + O_W1T);
        ushort* w2T    = (ushort*)(ws + O_W2T);

        hipMemsetAsync(ws + O_CNT, 0, 32768 + 4096, stream);   // cnt + pooled
        prep_kernel<<<(N_PREP + 255)/256, 256, 0, stream>>>(
            pos_emb, pred_emb, w1, w2, pos_bf, pred_bf, w1T, w2T);
        count_kernel<<<NMSG/256, 256, 0, stream>>>(a0, a1, bidir, cnt);
        scan_kernel<<<1, 1024, 0, stream>>>(cnt, off, cur);
        fill_kernel<<<NMSG/256, 256, 0, stream>>>(a0, a1, bidir, cur, idxl);
        msg_kernel<<<NF/FPB, 256, 0, stream>>>(a0, a1, pidx, bidir,
            pos_bf, pred_bf, w1T, b1, w2T, b2, msgbuf, (float*)0, 1);
        reduce_kernel<<<NNODE/(4*NPW), 256, 0, stream>>>(
            pos_emb, msgbuf, off, idxl, ln_g, ln_b, pooled);
        head_kernel<<<BB, 256, 0, stream>>>(pooled, lw1, lb1, lw2, lb2, (float*)d_out);
    } else {
        // fallback: atomic scatter path (round-2 structure)
        float*  agg    = (float*)ws;                            // 4 MB
        float*  pooled = (float*)(ws + 4194304);                // 4 KB
        ushort* pos_bf = (ushort*)(ws + 4198400);
        ushort* pred_bf= (ushort*)(ws + 4460544);
        ushort* w1T    = (ushort*)(ws + 4464128);
        ushort* w2T    = (ushort*)(ws + 4660736);

        hipMemsetAsync(ws, 0, 4198400, stream);
        prep_kernel<<<(N_PREP + 255)/256, 256, 0, stream>>>(
            pos_emb, pred_emb, w1, w2, pos_bf, pred_bf, w1T, w2T);
        msg_kernel<<<NF/FPB, 256, 0, stream>>>(a0, a1, pidx, bidir,
            pos_bf, pred_bf, w1T, b1, w2T, b2, (ushort*)0, agg, 0);
        ln_pool_kernel<<<BB*(SS/32), 256, 0, stream>>>(pos_emb, agg, ln_g, ln_b, pooled);
        head_kernel<<<BB, 256, 0, stream>>>(pooled, lw1, lb1, lw2, lb2, (float*)d_out);
    }
}